// Round 7
// baseline (267.936 us; speedup 1.0000x reference)
//
#include <hip/hip_runtime.h>

#define NVOX  160000
#define KOFF  27
#define EPSV  1e-5f
#define SLOPE 0.01f
#define NBLK  2500    // conv blocks: 2500*256 = 10,000 waves * 16 vox

using bf16x8 = __attribute__((ext_vector_type(8))) __bf16;
using f32x4  = __attribute__((ext_vector_type(4))) float;
using i32x4  = __attribute__((ext_vector_type(4))) int;
using u16    = unsigned short;
typedef __attribute__((ext_vector_type(4), aligned(4))) int i32x4u;
typedef __attribute__((ext_vector_type(2), aligned(4))) int i32x2u;

// Dtype evidence (rounds 2-6 counters): feat/weight/out/gamma are all f32
// (conv f32 path passes validation; WRITE_SIZE == N*32*4B). f32-only build.

// ---------------------------------------------------------------------------
// Pack W[27][32][32] f32 into MFMA B-fragment order (bf16).
// frag (k,f): couts f*16..f*16+15; lane L reg j holds B[c=(L>>4)*8+j][d=f*16+(L&15)]
// ---------------------------------------------------------------------------
__global__ void pack_weights(const float* __restrict__ w, u16* __restrict__ wp) {
    int tid = blockIdx.x * blockDim.x + threadIdx.x;   // 27648
    if (tid >= KOFF * 2 * 64 * 8) return;
    int j = tid & 7;
    int L = (tid >> 3) & 63;
    int f = (tid >> 9) & 1;
    int k = tid >> 10;
    int c = ((L >> 4) << 3) + j;
    int d = (f << 4) + (L & 15);
    __bf16 b = (__bf16)w[(k * 32 + c) * 32 + d];
    wp[tid] = __builtin_bit_cast(u16, b);
}

// ---------------------------------------------------------------------------
// Sparse conv via MFMA + fused BN-stats partials. Each wave owns 16 voxels.
// Phase 0: preload 27 neighbor ids per lane (contiguous row, 7 vector loads).
// Phase 1: 3 batches of 9 offsets; per offset a wave-uniform ballot skip
//          (empty ~70% of the time at 1.9% density); taken offsets issue 2
//          clamped dwordx4 gathers, drained into bf16 frags + 2 MFMAs.
// Epilogue: conv -> d_out, per-block per-channel sum/sumsq -> partials.
// ---------------------------------------------------------------------------
__global__ __launch_bounds__(256) void conv_f32(
    const float* __restrict__ feat,     // [N][32]
    const int*  __restrict__ nbr,       // [N][27]
    const i32x4* __restrict__ wp,       // packed B-frags
    float* __restrict__ out,            // [N][32] (d_out)
    float* __restrict__ partials)       // [2500][64]
{
    const int lane  = threadIdx.x & 63;
    const int wid   = (blockIdx.x * 256 + threadIdx.x) >> 6;   // 0..9999
    const int vbase = wid * 16;
    const int m = lane & 15;
    const int q = lane >> 4;

    // ---- phase 0: this lane's full neighbor row ----
    const int* row = nbr + (size_t)(vbase + m) * KOFF;
    int id[27];
    *(i32x4u*)(id +  0) = *(const i32x4u*)(row +  0);
    *(i32x4u*)(id +  4) = *(const i32x4u*)(row +  4);
    *(i32x4u*)(id +  8) = *(const i32x4u*)(row +  8);
    *(i32x4u*)(id + 12) = *(const i32x4u*)(row + 12);
    *(i32x4u*)(id + 16) = *(const i32x4u*)(row + 16);
    *(i32x4u*)(id + 20) = *(const i32x4u*)(row + 20);
    *(i32x2u*)(id + 24) = *(const i32x2u*)(row + 24);
    id[26] = row[26];

    f32x4 acc0 = {}, acc1 = {};

    // ---- phase 1: 3 batches of 9, ballot-gated gathers then drain+MFMA ----
#pragma unroll
    for (int b = 0; b < 3; ++b) {
        f32x4 lo[9], hi[9];
#pragma unroll
        for (int j = 0; j < 9; ++j) {
            int k = b * 9 + j;
            if (__ballot(id[k] >= 0)) {            // wave-uniform scalar branch
                int v_id = id[k];
                int safe = v_id >= 0 ? v_id : 0;   // invalid -> hot row 0 (L1)
                const f32x4* fp = (const f32x4*)(feat + (size_t)safe * 32 + q * 8);
                lo[j] = fp[0];
                hi[j] = fp[1];
            }
        }
#pragma unroll
        for (int j = 0; j < 9; ++j) {
            int k = b * 9 + j;
            if (__ballot(id[k] >= 0)) {
                bf16x8 t;
#pragma unroll
                for (int jj = 0; jj < 4; ++jj) {
                    t[jj]     = (__bf16)lo[j][jj];
                    t[4 + jj] = (__bf16)hi[j][jj];
                }
                bf16x8 z = {};
                bf16x8 a = (id[k] < 0) ? z : t;
                i32x4 b0r = wp[(k * 2 + 0) * 64 + lane];
                i32x4 b1r = wp[(k * 2 + 1) * 64 + lane];
                bf16x8 b0 = __builtin_bit_cast(bf16x8, b0r);
                bf16x8 b1 = __builtin_bit_cast(bf16x8, b1r);
                acc0 = __builtin_amdgcn_mfma_f32_16x16x32_bf16(a, b0, acc0, 0, 0, 0);
                acc1 = __builtin_amdgcn_mfma_f32_16x16x32_bf16(a, b1, acc1, 0, 0, 0);
            }
        }
    }

    // ---- epilogue: store conv + per-channel stats ----
    // C/D: row(voxel) = q*4 + r, col(cout) = m (+16 for acc1)
    float s0 = 0, s1 = 0, sq0 = 0, sq1 = 0;
#pragma unroll
    for (int r = 0; r < 4; ++r) {
        int v = vbase + q * 4 + r;
        float x0 = acc0[r], x1 = acc1[r];
        s0 += x0; sq0 += x0 * x0;
        s1 += x1; sq1 += x1 * x1;
        out[v * 32 + m]      = x0;
        out[v * 32 + 16 + m] = x1;
    }
    // reduce over q (lanes sharing m): xor-16 then xor-32
    s0  += __shfl_xor(s0, 16, 64);  s0  += __shfl_xor(s0, 32, 64);
    s1  += __shfl_xor(s1, 16, 64);  s1  += __shfl_xor(s1, 32, 64);
    sq0 += __shfl_xor(sq0, 16, 64); sq0 += __shfl_xor(sq0, 32, 64);
    sq1 += __shfl_xor(sq1, 16, 64); sq1 += __shfl_xor(sq1, 32, 64);

    __shared__ float red[4][64];
    int w = threadIdx.x >> 6;
    if (lane < 16) {
        red[w][m]      = s0;   // sum, ch m
        red[w][16 + m] = s1;   // sum, ch 16+m
        red[w][32 + m] = sq0;  // sumsq, ch m
        red[w][48 + m] = sq1;  // sumsq, ch 16+m
    }
    __syncthreads();
    if (threadIdx.x < 64) {
        int t = threadIdx.x;
        partials[(size_t)blockIdx.x * 64 + t] =
            red[0][t] + red[1][t] + red[2][t] + red[3][t];
    }
}

// ---------------------------------------------------------------------------
// Reduce 2500 partials -> scale/shift (one block of 256)
// ---------------------------------------------------------------------------
__global__ __launch_bounds__(256) void finalize_stats(
    const float* __restrict__ partials, const float* __restrict__ gamma,
    const float* __restrict__ beta, float* __restrict__ sc)
{
    __shared__ float st[256];
    int t = threadIdx.x;
    int c = t & 63, part = t >> 6;
    float a = 0.f;
    for (int p = part; p < NBLK; p += 4) a += partials[(size_t)p * 64 + c];
    st[t] = a;
    __syncthreads();
    if (t < 64) st[t] = st[t] + st[t + 64] + st[t + 128] + st[t + 192];
    __syncthreads();
    if (t < 32) {
        float mean = st[t] * (1.f / NVOX);
        float var  = st[32 + t] * (1.f / NVOX) - mean * mean;
        float rstd = rsqrtf(var + EPSV);
        float scale = gamma[t] * rstd;
        sc[t]      = scale;
        sc[32 + t] = beta[t] - mean * scale;
    }
}

// ---------------------------------------------------------------------------
// BN + LeakyReLU over d_out, in place
// ---------------------------------------------------------------------------
__global__ __launch_bounds__(256) void apply_bn(
    f32x4* __restrict__ o, const float* __restrict__ sc)
{
    __shared__ float s[64];
    int t = threadIdx.x;
    if (t < 64) s[t] = sc[t];
    __syncthreads();
    int i = blockIdx.x * 256 + t;
#pragma unroll
    for (int rep = 0; rep < 2; ++rep) {
        int i2 = i * 2 + rep;               // 1,280,000 vec4 total
        f32x4 v = o[i2];
        int c0 = (i2 & 7) * 4;
        f32x4 r;
#pragma unroll
        for (int j = 0; j < 4; ++j) {
            float y = v[j] * s[c0 + j] + s[32 + c0 + j];
            r[j] = (y >= 0.f) ? y : SLOPE * y;
        }
        o[i2] = r;
    }
}

// ---------------------------------------------------------------------------
extern "C" void kernel_launch(void* const* d_in, const int* in_sizes, int n_in,
                              void* d_out, int out_size, void* d_ws, size_t ws_size,
                              hipStream_t stream) {
    const float* feat  = (const float*)d_in[0];  // [N][32] f32
    const int*   nbr   = (const int*)d_in[1];    // [N][27] int32
    const float* w     = (const float*)d_in[2];  // [27][32][32] f32
    // d_in[3] = bias: cancels exactly in BN — unused
    const float* gamma = (const float*)d_in[4];
    const float* beta  = (const float*)d_in[5];

    // ws is ~256 MB (fill-kernel evidence, round 6); round 4's corruption was
    // the scratch-backed dynamic local array, not ws overflow.
    char* ws = (char*)d_ws;
    float* partials = (float*)ws;                     // 2500*64*4 = 640,000 B
    u16*   wp       = (u16*)(ws + 640000);            // 55,296 B
    float* sc       = (float*)(ws + 640000 + 55296);  // 256 B

    pack_weights<<<108, 256, 0, stream>>>(w, wp);
    conv_f32<<<NBLK, 256, 0, stream>>>(feat, nbr, (const i32x4*)wp,
                                       (float*)d_out, partials);
    finalize_stats<<<1, 256, 0, stream>>>(partials, gamma, beta, sc);
    apply_bn<<<2500, 256, 0, stream>>>((f32x4*)d_out, sc);
}

// Round 8
// 123.319 us; speedup vs baseline: 2.1727x; 2.1727x over previous
//
#include <hip/hip_runtime.h>

#define NVOX  160000
#define KOFF  27
#define EPSV  1e-5f
#define SLOPE 0.01f
#define NBLK  2500    // conv blocks: 2500*256 = 10,000 waves * 16 vox
#define PADP  2560    // padded partials row stride (floats), 256B-aligned

using bf16x8 = __attribute__((ext_vector_type(8))) __bf16;
using f32x4  = __attribute__((ext_vector_type(4))) float;
using i32x4  = __attribute__((ext_vector_type(4))) int;
using u16    = unsigned short;
typedef __attribute__((ext_vector_type(4), aligned(4))) int i32x4u;
typedef __attribute__((ext_vector_type(2), aligned(4))) int i32x2u;

// Dtype evidence (rounds 2-6 counters): feat/weight/out/gamma are all f32.

// ---------------------------------------------------------------------------
// Pack W[27][32][32] f32 into MFMA B-fragment order (bf16).
// frag (k,f): couts f*16..f*16+15; lane L reg j holds B[c=(L>>4)*8+j][d=f*16+(L&15)]
// ---------------------------------------------------------------------------
__global__ void pack_weights(const float* __restrict__ w, u16* __restrict__ wp) {
    int tid = blockIdx.x * blockDim.x + threadIdx.x;   // 27648
    if (tid >= KOFF * 2 * 64 * 8) return;
    int j = tid & 7;
    int L = (tid >> 3) & 63;
    int f = (tid >> 9) & 1;
    int k = tid >> 10;
    int c = ((L >> 4) << 3) + j;
    int d = (f << 4) + (L & 15);
    __bf16 b = (__bf16)w[(k * 32 + c) * 32 + d];
    wp[tid] = __builtin_bit_cast(u16, b);
}

// ---------------------------------------------------------------------------
// Sparse conv via MFMA + fused BN-stats partials. Each wave owns 16 voxels.
// Phase 0: preload 27 neighbor ids per lane (contiguous row, 7 vector loads).
// Phase 1: 3 batches of 9 offsets; wave-uniform ballot skip per offset;
//          taken offsets: 2 clamped dwordx4 gathers -> bf16 frag -> 2 MFMAs.
// Epilogue: conv -> d_out; per-channel sum/sumsq -> TRANSPOSED partials
//           [64][PADP] so the reduce kernel reads coalesced rows.
// ---------------------------------------------------------------------------
__global__ __launch_bounds__(256) void conv_f32(
    const float* __restrict__ feat,     // [N][32]
    const int*  __restrict__ nbr,       // [N][27]
    const i32x4* __restrict__ wp,       // packed B-frags
    float* __restrict__ out,            // [N][32] (d_out)
    float* __restrict__ partials)       // [64][PADP]
{
    const int lane  = threadIdx.x & 63;
    const int wid   = (blockIdx.x * 256 + threadIdx.x) >> 6;   // 0..9999
    const int vbase = wid * 16;
    const int m = lane & 15;
    const int q = lane >> 4;

    // ---- phase 0: this lane's full neighbor row ----
    const int* row = nbr + (size_t)(vbase + m) * KOFF;
    int id[27];
    *(i32x4u*)(id +  0) = *(const i32x4u*)(row +  0);
    *(i32x4u*)(id +  4) = *(const i32x4u*)(row +  4);
    *(i32x4u*)(id +  8) = *(const i32x4u*)(row +  8);
    *(i32x4u*)(id + 12) = *(const i32x4u*)(row + 12);
    *(i32x4u*)(id + 16) = *(const i32x4u*)(row + 16);
    *(i32x4u*)(id + 20) = *(const i32x4u*)(row + 20);
    *(i32x2u*)(id + 24) = *(const i32x2u*)(row + 24);
    id[26] = row[26];

    f32x4 acc0 = {}, acc1 = {};

    // ---- phase 1: 3 batches of 9, ballot-gated gathers then drain+MFMA ----
#pragma unroll
    for (int b = 0; b < 3; ++b) {
        f32x4 lo[9], hi[9];
#pragma unroll
        for (int j = 0; j < 9; ++j) {
            int k = b * 9 + j;
            if (__ballot(id[k] >= 0)) {            // wave-uniform scalar branch
                int v_id = id[k];
                int safe = v_id >= 0 ? v_id : 0;   // invalid -> hot row 0 (L1)
                const f32x4* fp = (const f32x4*)(feat + (size_t)safe * 32 + q * 8);
                lo[j] = fp[0];
                hi[j] = fp[1];
            }
        }
#pragma unroll
        for (int j = 0; j < 9; ++j) {
            int k = b * 9 + j;
            if (__ballot(id[k] >= 0)) {
                bf16x8 t;
#pragma unroll
                for (int jj = 0; jj < 4; ++jj) {
                    t[jj]     = (__bf16)lo[j][jj];
                    t[4 + jj] = (__bf16)hi[j][jj];
                }
                bf16x8 z = {};
                bf16x8 a = (id[k] < 0) ? z : t;
                i32x4 b0r = wp[(k * 2 + 0) * 64 + lane];
                i32x4 b1r = wp[(k * 2 + 1) * 64 + lane];
                bf16x8 b0 = __builtin_bit_cast(bf16x8, b0r);
                bf16x8 b1 = __builtin_bit_cast(bf16x8, b1r);
                acc0 = __builtin_amdgcn_mfma_f32_16x16x32_bf16(a, b0, acc0, 0, 0, 0);
                acc1 = __builtin_amdgcn_mfma_f32_16x16x32_bf16(a, b1, acc1, 0, 0, 0);
            }
        }
    }

    // ---- epilogue: store conv + per-channel stats ----
    // C/D: row(voxel) = q*4 + r, col(cout) = m (+16 for acc1)
    float s0 = 0, s1 = 0, sq0 = 0, sq1 = 0;
#pragma unroll
    for (int r = 0; r < 4; ++r) {
        int v = vbase + q * 4 + r;
        float x0 = acc0[r], x1 = acc1[r];
        s0 += x0; sq0 += x0 * x0;
        s1 += x1; sq1 += x1 * x1;
        out[v * 32 + m]      = x0;
        out[v * 32 + 16 + m] = x1;
    }
    // reduce over q (lanes sharing m)
    s0  += __shfl_xor(s0, 16, 64);  s0  += __shfl_xor(s0, 32, 64);
    s1  += __shfl_xor(s1, 16, 64);  s1  += __shfl_xor(s1, 32, 64);
    sq0 += __shfl_xor(sq0, 16, 64); sq0 += __shfl_xor(sq0, 32, 64);
    sq1 += __shfl_xor(sq1, 16, 64); sq1 += __shfl_xor(sq1, 32, 64);

    __shared__ float red[4][64];
    int w = threadIdx.x >> 6;
    if (lane < 16) {
        red[w][m]      = s0;   // sum, ch m
        red[w][16 + m] = s1;   // sum, ch 16+m
        red[w][32 + m] = sq0;  // sumsq, ch m
        red[w][48 + m] = sq1;  // sumsq, ch 16+m
    }
    __syncthreads();
    if (threadIdx.x < 64) {
        int t = threadIdx.x;
        // transposed: row t (channel-slot), column blockIdx.x
        partials[(size_t)t * PADP + blockIdx.x] =
            red[0][t] + red[1][t] + red[2][t] + red[3][t];
    }
}

// ---------------------------------------------------------------------------
// 64 blocks: block c sums its contiguous partials row -> stats[c]
// ---------------------------------------------------------------------------
__global__ __launch_bounds__(256) void reduce_stats(
    const float* __restrict__ partials, float* __restrict__ stats)
{
    const float* prow = partials + (size_t)blockIdx.x * PADP;
    float s = 0.f;
    for (int p = threadIdx.x; p < NBLK; p += 256) s += prow[p];
#pragma unroll
    for (int off = 1; off < 64; off <<= 1) s += __shfl_xor(s, off, 64);
    __shared__ float sd[4];
    int lane = threadIdx.x & 63, w = threadIdx.x >> 6;
    if (lane == 0) sd[w] = s;
    __syncthreads();
    if (threadIdx.x == 0) stats[blockIdx.x] = sd[0] + sd[1] + sd[2] + sd[3];
}

// ---------------------------------------------------------------------------
// BN + LeakyReLU over d_out, in place; scale/shift derived per block from
// stats[64] (512B, L2-broadcast) — saves a dispatch.
// ---------------------------------------------------------------------------
__global__ __launch_bounds__(256) void apply_bn(
    f32x4* __restrict__ o, const float* __restrict__ stats,
    const float* __restrict__ gamma, const float* __restrict__ beta)
{
    __shared__ float s[64];
    int t = threadIdx.x;
    if (t < 32) {
        float mean = stats[t] * (1.f / NVOX);
        float var  = stats[32 + t] * (1.f / NVOX) - mean * mean;
        float rstd = rsqrtf(var + EPSV);
        float scale = gamma[t] * rstd;
        s[t]      = scale;
        s[32 + t] = beta[t] - mean * scale;
    }
    __syncthreads();
    int i = blockIdx.x * 256 + t;
#pragma unroll
    for (int rep = 0; rep < 2; ++rep) {
        int i2 = i * 2 + rep;               // 1,280,000 vec4 total
        f32x4 v = o[i2];
        int c0 = (i2 & 7) * 4;
        f32x4 r;
#pragma unroll
        for (int j = 0; j < 4; ++j) {
            float y = v[j] * s[c0 + j] + s[32 + c0 + j];
            r[j] = (y >= 0.f) ? y : SLOPE * y;
        }
        o[i2] = r;
    }
}

// ---------------------------------------------------------------------------
extern "C" void kernel_launch(void* const* d_in, const int* in_sizes, int n_in,
                              void* d_out, int out_size, void* d_ws, size_t ws_size,
                              hipStream_t stream) {
    const float* feat  = (const float*)d_in[0];  // [N][32] f32
    const int*   nbr   = (const int*)d_in[1];    // [N][27] int32
    const float* w     = (const float*)d_in[2];  // [27][32][32] f32
    // d_in[3] = bias: cancels exactly in BN — unused
    const float* gamma = (const float*)d_in[4];
    const float* beta  = (const float*)d_in[5];

    // ws ~256 MB (fill-kernel evidence, round 6). Avoid dynamic-indexed local
    // arrays (round 4 scratch corruption).
    char* ws = (char*)d_ws;
    float* partials = (float*)ws;                       // 64*2560*4 = 655,360 B
    u16*   wp       = (u16*)(ws + 655360);              // 55,296 B
    float* stats    = (float*)(ws + 655360 + 55296);    // 256 B

    pack_weights<<<108, 256, 0, stream>>>(w, wp);
    conv_f32<<<NBLK, 256, 0, stream>>>(feat, nbr, (const i32x4*)wp,
                                       (float*)d_out, partials);
    reduce_stats<<<64, 256, 0, stream>>>(partials, stats);
    apply_bn<<<2500, 256, 0, stream>>>((f32x4*)d_out, stats, gamma, beta);
}